// Round 19
// baseline (27.975 us; speedup 1.0000x reference)
//
#include <hip/hip_runtime.h>

// ROI max-pool (aspect-preserving "OCR" variant) — separable two-phase, v16.
// feats: (B=4, C=128, H=64, W=512) fp32
// rois:  (N, 5) fp32 = [batch, x1, y1, x2, y2] image coords, spatial scale 0.25
// out:   (N, C, PH=8, PW=32) fp32
//
// R16 body (exact-nh staging, best @23.9us) with TWO independent 1-wave items
// per 128-thread workgroup (per-wave LDS slice, NO __syncthreads — same-wave
// LDS write->read ordered by inline s_waitcnt lgkmcnt(0) + sched_barrier(0)).
// Probes the wg-slot hypothesis: if CUs allocate max 16 workgroup slots,
// 1-wave wgs cap at 16 waves/CU (the observed ~60% occupancy ceiling);
// 2-wave wgs restore 32 waves/CU with unchanged item granularity.

#define PHB 8
#define PWB 32
#define CHB 8           // channels per item
#define WST 116         // staged width cap: ceil(32*bsw) <= 108, +3 align
#define BLK 128         // 2 waves = 2 independent items

static __device__ __forceinline__ float4 max4(float4 a, float4 b) {
    float4 r;
    r.x = fmaxf(a.x, b.x); r.y = fmaxf(a.y, b.y);
    r.z = fmaxf(a.z, b.z); r.w = fmaxf(a.w, b.w);
    return r;
}

template<int NH>
static __device__ __forceinline__ void stage_rows(
    const float* __restrict__ plane, int plane_stride, int Wc,
    int hs, int goff, int wp4, float* __restrict__ S, int cslot)
{
    float4 v[NH][4];
#pragma unroll
    for (int rr = 0; rr < NH; ++rr) {
        int o = (hs + rr) * Wc + goff;         // 16B-aligned, in-row
#pragma unroll
        for (int j = 0; j < 4; ++j)
            v[rr][j] = *reinterpret_cast<const float4*>(
                plane + (size_t)(2 * j) * plane_stride + o);
    }
#pragma unroll
    for (int j = 0; j < 4; ++j) {
        float4 rm = v[0][j];
#pragma unroll
        for (int rr = 1; rr < NH; ++rr) rm = max4(rm, v[rr][j]);
        *reinterpret_cast<float4*>(&S[(cslot + 2 * j) * WST + wp4]) = rm;
    }
}

__global__ __launch_bounds__(BLK) void ocr_roi_pool_kernel(
    const float* __restrict__ feats,
    const float* __restrict__ rois,
    float* __restrict__ out,
    int Cc, int Hc, int Wc)
{
#pragma clang fp contract(off)
    __shared__ float smax[2][CHB * WST + 8];   // per-wave slice, +8 pad

    int t    = threadIdx.x;
    int wid  = t >> 6;                 // which item (wave) in this block
    int lane = t & 63;

    int item = blockIdx.x * 2 + wid;   // ((n*8 + ph)*16 + cg)
    int cg = item & 15;
    int ph = (item >> 4) & 7;
    int n  = item >> 7;
    int c0 = cg * CHB;

    // ---- ROI params: wave-uniform -> scalar ----
    const float* r = rois + n * 5;
    int rb  = (int)r[0];
    int rsw = (int)floorf(r[1] * 0.25f + 0.5f);
    int rsh = (int)floorf(r[2] * 0.25f + 0.5f);
    int rew = (int)floorf(r[3] * 0.25f + 0.5f);
    int reh = (int)floorf(r[4] * 0.25f + 0.5f);

    int roi_w = max(rew - rsw + 1, 1);
    int roi_h = max(reh - rsh + 1, 1);
    int rpw   = (PHB * roi_w + roi_h - 1) / roi_h;

    float bsh = (float)roi_h / (float)PHB;
    float bsw = (float)roi_w / (float)rpw;

    // h-range for this ph (wave-uniform), exact reference math
    int hs = (int)floorf((float)ph * bsh) + rsh;
    int he = (int)ceilf((float)(ph + 1) * bsh) + rsh;
    hs = min(max(hs, 0), Hc);
    he = min(max(he, 0), Hc);
    int nh = he - hs;                  // 0..5, wave-uniform

    // staged w-window: covers every NON-PAD bin's reads; 4-aligned base.
    int wlo = min(max(rsw, 0), Wc);
    int whi = (int)ceilf((float)PWB * bsw) + rsw;
    whi = min(whi, rew + 4);
    whi = min(max(whi, 0), Wc);
    int wlo_al = wlo & ~3;
    int wwid = min(whi - wlo_al, WST);

    int lane_w = lane & 31;
    int cslot  = lane >> 5;            // 0..1
    int wp4    = lane_w * 4;           // this lane's 4-column slot

    const int plane_stride = Hc * Wc;  // 32768
    float* S = smax[wid];

    // ---- Phase 1: rowmax -> LDS (exact-nh unroll, wave-uniform branch) ----
    if (nh > 0 && wp4 < wwid) {
        const float* plane =
            feats + ((size_t)(rb * Cc + c0 + cslot) * Hc) * Wc;
        int goff = wlo_al + wp4;
        switch (nh) {
        case 1:  stage_rows<1>(plane, plane_stride, Wc, hs, goff, wp4, S, cslot); break;
        case 2:  stage_rows<2>(plane, plane_stride, Wc, hs, goff, wp4, S, cslot); break;
        case 3:  stage_rows<3>(plane, plane_stride, Wc, hs, goff, wp4, S, cslot); break;
        case 4:  stage_rows<4>(plane, plane_stride, Wc, hs, goff, wp4, S, cslot); break;
        default: stage_rows<5>(plane, plane_stride, Wc, hs, goff, wp4, S, cslot); break;
        }
    }
    // Same-wave LDS write->read ordering (no cross-wave sharing, so no
    // barrier): drain LDS pipe, pin compiler ordering (guide rule 18).
    asm volatile("s_waitcnt lgkmcnt(0)" ::: "memory");
    __builtin_amdgcn_sched_barrier(0);

    // ---- Phase 2: colmax from LDS (fixed 5-wide masked unroll), store ----
    int pw = lane_w;
    int ws = (int)floorf((float)pw * bsw) + rsw;
    int we = (int)ceilf((float)(pw + 1) * bsw) + rsw;
    ws = min(max(ws, 0), Wc);
    we = min(max(we, 0), Wc);

    bool pad   = (ws >= rew);
    bool empty = (he <= hs) || (we <= ws);

    size_t obase = (((size_t)n * Cc + c0 + cslot) * PHB + ph) * PWB + pw;
    if (pad || empty) {
#pragma unroll
        for (int j = 0; j < 4; ++j)
            out[obase + (size_t)(2 * j) * (PHB * PWB)] = 0.0f;
    } else {
        int base = ws - wlo_al;        // >= 0
        int nw   = we - ws;            // 1..5 (bsw <= 3.375)
#pragma unroll
        for (int j = 0; j < 4; ++j) {
            const float* row = &S[(cslot + 2 * j) * WST + base];
            float m = -1e37f;
#pragma unroll
            for (int i = 0; i < 5; ++i) {        // 5 independent ds_reads,
                float v = row[i];                // masked beyond nw
                m = (i < nw) ? fmaxf(m, v) : m;
            }
            out[obase + (size_t)(2 * j) * (PHB * PWB)] = m;
        }
    }
}

extern "C" void kernel_launch(void* const* d_in, const int* in_sizes, int n_in,
                              void* d_out, int out_size, void* d_ws, size_t ws_size,
                              hipStream_t stream) {
    const float* feats = (const float*)d_in[0];
    const float* rois  = (const float*)d_in[1];
    float* out = (float*)d_out;

    const int Cc = 128, Hc = 64, Wc = 512;
    int nroi = in_sizes[1] / 5;
    int items = nroi * PHB * (Cc / CHB);   // 32768
    int blocks = items / 2;                // 16384 x 2 waves

    ocr_roi_pool_kernel<<<blocks, BLK, 0, stream>>>(feats, rois, out, Cc, Hc, Wc);
}

// Round 20
// 26.593 us; speedup vs baseline: 1.0520x; 1.0520x over previous
//
#include <hip/hip_runtime.h>

// ROI max-pool (aspect-preserving "OCR" variant) — separable two-phase, v17.
// feats: (B=4, C=128, H=64, W=512) fp32
// rois:  (N, 5) fp32 = [batch, x1, y1, x2, y2] image coords, spatial scale 0.25
// out:   (N, C, PH=8, PW=32) fp32
//
// R16 exact-NH body with CHB=16: item = (n, ph, channel-group of 16), one
// wave; each cslot stages 8 channels (stride 2). Halves item count (32768 ->
// 16384) -> halves total per-item fixed cost (ROI s_load + divide + floor/
// ceil geometry ~350cy each) and doubles per-wave load MLP; trades wave
// count (32 -> 16 blocks/CU). A/B vs R16 (23.9us) closes the CHB axis.
// Phase 2: w-max from LDS, 5-wide masked unroll (nw <= 5), 8 outputs/lane.

#define PHB 8
#define PWB 32
#define CHB 16          // channels per block
#define WST 116         // staged width cap: ceil(32*bsw) <= 108, +3 align
#define BLK 64

static __device__ __forceinline__ float4 max4(float4 a, float4 b) {
    float4 r;
    r.x = fmaxf(a.x, b.x); r.y = fmaxf(a.y, b.y);
    r.z = fmaxf(a.z, b.z); r.w = fmaxf(a.w, b.w);
    return r;
}

template<int NH>
static __device__ __forceinline__ void stage_rows(
    const float* __restrict__ plane, int plane_stride, int Wc,
    int hs, int goff, int wp4, float* __restrict__ S, int cslot)
{
    // 8 channels per cslot (stride 2), NH rows each: 8*NH independent dwordx4
#pragma unroll
    for (int j = 0; j < 8; ++j) {
        const float* pj = plane + (size_t)(2 * j) * plane_stride;
        float4 v[NH];
#pragma unroll
        for (int rr = 0; rr < NH; ++rr) {
            int o = (hs + rr) * Wc + goff;     // 16B-aligned, in-row
            v[rr] = *reinterpret_cast<const float4*>(pj + o);
        }
        float4 rm = v[0];
#pragma unroll
        for (int rr = 1; rr < NH; ++rr) rm = max4(rm, v[rr]);
        *reinterpret_cast<float4*>(&S[(cslot + 2 * j) * WST + wp4]) = rm;
    }
}

__global__ __launch_bounds__(BLK) void ocr_roi_pool_kernel(
    const float* __restrict__ feats,
    const float* __restrict__ rois,
    float* __restrict__ out,
    int Cc, int Hc, int Wc)
{
#pragma clang fp contract(off)
    __shared__ float smax[CHB * WST + 8];   // +8: phase-2 unroll over-read pad

    int b  = blockIdx.x;               // ((n*8 + ph)*8 + cg)
    int cg = b & 7;
    int ph = (b >> 3) & 7;
    int n  = b >> 6;
    int c0 = cg * CHB;

    // ---- ROI params: block-uniform -> scalar ----
    const float* r = rois + n * 5;
    int rb  = (int)r[0];
    int rsw = (int)floorf(r[1] * 0.25f + 0.5f);
    int rsh = (int)floorf(r[2] * 0.25f + 0.5f);
    int rew = (int)floorf(r[3] * 0.25f + 0.5f);
    int reh = (int)floorf(r[4] * 0.25f + 0.5f);

    int roi_w = max(rew - rsw + 1, 1);
    int roi_h = max(reh - rsh + 1, 1);
    int rpw   = (PHB * roi_w + roi_h - 1) / roi_h;

    float bsh = (float)roi_h / (float)PHB;
    float bsw = (float)roi_w / (float)rpw;

    // h-range for this ph (uniform over block), exact reference math
    int hs = (int)floorf((float)ph * bsh) + rsh;
    int he = (int)ceilf((float)(ph + 1) * bsh) + rsh;
    hs = min(max(hs, 0), Hc);
    he = min(max(he, 0), Hc);
    int nh = he - hs;                  // 0..5, wave-uniform

    // staged w-window: covers every NON-PAD bin's reads; 4-aligned base.
    int wlo = min(max(rsw, 0), Wc);
    int whi = (int)ceilf((float)PWB * bsw) + rsw;
    whi = min(whi, rew + 4);
    whi = min(max(whi, 0), Wc);
    int wlo_al = wlo & ~3;
    int wwid = min(whi - wlo_al, WST);

    int t      = threadIdx.x;
    int lane_w = t & 31;
    int cslot  = t >> 5;               // 0..1
    int wp4    = lane_w * 4;           // this lane's 4-column slot

    const int plane_stride = Hc * Wc;  // 32768

    // ---- Phase 1: rowmax -> LDS (exact-nh unroll, wave-uniform branch) ----
    if (nh > 0 && wp4 < wwid) {
        const float* plane =
            feats + ((size_t)(rb * Cc + c0 + cslot) * Hc) * Wc;
        int goff = wlo_al + wp4;
        switch (nh) {
        case 1:  stage_rows<1>(plane, plane_stride, Wc, hs, goff, wp4, smax, cslot); break;
        case 2:  stage_rows<2>(plane, plane_stride, Wc, hs, goff, wp4, smax, cslot); break;
        case 3:  stage_rows<3>(plane, plane_stride, Wc, hs, goff, wp4, smax, cslot); break;
        case 4:  stage_rows<4>(plane, plane_stride, Wc, hs, goff, wp4, smax, cslot); break;
        default: stage_rows<5>(plane, plane_stride, Wc, hs, goff, wp4, smax, cslot); break;
        }
    }
    __syncthreads();

    // ---- Phase 2: colmax from LDS (fixed 5-wide masked unroll), store ----
    int pw = lane_w;
    int ws = (int)floorf((float)pw * bsw) + rsw;
    int we = (int)ceilf((float)(pw + 1) * bsw) + rsw;
    ws = min(max(ws, 0), Wc);
    we = min(max(we, 0), Wc);

    bool pad   = (ws >= rew);
    bool empty = (he <= hs) || (we <= ws);

    size_t obase = (((size_t)n * Cc + c0 + cslot) * PHB + ph) * PWB + pw;
    if (pad || empty) {
#pragma unroll
        for (int j = 0; j < 8; ++j)
            out[obase + (size_t)(2 * j) * (PHB * PWB)] = 0.0f;
    } else {
        int base = ws - wlo_al;        // >= 0
        int nw   = we - ws;            // 1..5 (bsw <= 3.375)
#pragma unroll
        for (int j = 0; j < 8; ++j) {
            const float* row = &smax[(cslot + 2 * j) * WST + base];
            float m = -1e37f;
#pragma unroll
            for (int i = 0; i < 5; ++i) {        // 5 independent ds_reads,
                float v = row[i];                // masked beyond nw
                m = (i < nw) ? fmaxf(m, v) : m;
            }
            out[obase + (size_t)(2 * j) * (PHB * PWB)] = m;
        }
    }
}

extern "C" void kernel_launch(void* const* d_in, const int* in_sizes, int n_in,
                              void* d_out, int out_size, void* d_ws, size_t ws_size,
                              hipStream_t stream) {
    const float* feats = (const float*)d_in[0];
    const float* rois  = (const float*)d_in[1];
    float* out = (float*)d_out;

    const int Cc = 128, Hc = 64, Wc = 512;
    int nroi = in_sizes[1] / 5;
    int blocks = nroi * PHB * (Cc / CHB);   // 16384

    ocr_roi_pool_kernel<<<blocks, BLK, 0, stream>>>(feats, rois, out, Cc, Hc, Wc);
}

// Round 21
// 24.121 us; speedup vs baseline: 1.1598x; 1.1025x over previous
//
#include <hip/hip_runtime.h>

// ROI max-pool (aspect-preserving "OCR" variant) — separable two-phase, v14
// (R16 optimum, resubmitted after R17-R19 A/Bs all regressed or were neutral).
// feats: (B=4, C=128, H=64, W=512) fp32
// rois:  (N, 5) fp32 = [batch, x1, y1, x2, y2] image coords, spatial scale 0.25
// out:   (N, C, PH=8, PW=32) fp32
//
// Item = (roi, ph, channel-group of 8), one wave, 32768 single-wave blocks
// (32 waves/CU; finer/coarser granularity both measured worse).
// Phase 1: EXACT-nh staging — nh = he-hs is wave-uniform <= 5, scalar 5-way
// branch to a template body issuing exactly 4*nh independent dwordx4 in tight
// order (FETCH ~43 MB = line-granular minimum), max-tree, one float4 LDS
// write per channel. Phase 2: w-max from LDS, 5-wide masked unroll (nw <= 5).

#define PHB 8
#define PWB 32
#define CHB 8           // channels per block
#define WST 116         // staged width cap: ceil(32*bsw) <= 108, +3 align
#define BLK 64

static __device__ __forceinline__ float4 max4(float4 a, float4 b) {
    float4 r;
    r.x = fmaxf(a.x, b.x); r.y = fmaxf(a.y, b.y);
    r.z = fmaxf(a.z, b.z); r.w = fmaxf(a.w, b.w);
    return r;
}

template<int NH>
static __device__ __forceinline__ void stage_rows(
    const float* __restrict__ plane, int plane_stride, int Wc,
    int hs, int goff, int wp4, float* __restrict__ smax, int cslot)
{
    float4 v[NH][4];
#pragma unroll
    for (int rr = 0; rr < NH; ++rr) {
        int o = (hs + rr) * Wc + goff;         // 16B-aligned, in-row
#pragma unroll
        for (int j = 0; j < 4; ++j)
            v[rr][j] = *reinterpret_cast<const float4*>(
                plane + (size_t)(2 * j) * plane_stride + o);
    }
#pragma unroll
    for (int j = 0; j < 4; ++j) {
        float4 rm = v[0][j];
#pragma unroll
        for (int rr = 1; rr < NH; ++rr) rm = max4(rm, v[rr][j]);
        *reinterpret_cast<float4*>(&smax[(cslot + 2 * j) * WST + wp4]) = rm;
    }
}

__global__ __launch_bounds__(BLK) void ocr_roi_pool_kernel(
    const float* __restrict__ feats,
    const float* __restrict__ rois,
    float* __restrict__ out,
    int Cc, int Hc, int Wc)
{
#pragma clang fp contract(off)
    __shared__ float smax[CHB * WST + 8];   // +8: phase-2 unroll over-read pad

    int b  = blockIdx.x;               // ((n*8 + ph)*16 + cg)
    int cg = b & 15;
    int ph = (b >> 4) & 7;
    int n  = b >> 7;
    int c0 = cg * CHB;

    // ---- ROI params: block-uniform -> scalar ----
    const float* r = rois + n * 5;
    int rb  = (int)r[0];
    int rsw = (int)floorf(r[1] * 0.25f + 0.5f);
    int rsh = (int)floorf(r[2] * 0.25f + 0.5f);
    int rew = (int)floorf(r[3] * 0.25f + 0.5f);
    int reh = (int)floorf(r[4] * 0.25f + 0.5f);

    int roi_w = max(rew - rsw + 1, 1);
    int roi_h = max(reh - rsh + 1, 1);
    int rpw   = (PHB * roi_w + roi_h - 1) / roi_h;

    float bsh = (float)roi_h / (float)PHB;
    float bsw = (float)roi_w / (float)rpw;

    // h-range for this ph (uniform over block), exact reference math
    int hs = (int)floorf((float)ph * bsh) + rsh;
    int he = (int)ceilf((float)(ph + 1) * bsh) + rsh;
    hs = min(max(hs, 0), Hc);
    he = min(max(he, 0), Hc);
    int nh = he - hs;                  // 0..5, wave-uniform

    // staged w-window: covers every NON-PAD bin's reads; 4-aligned base.
    int wlo = min(max(rsw, 0), Wc);
    int whi = (int)ceilf((float)PWB * bsw) + rsw;
    whi = min(whi, rew + 4);
    whi = min(max(whi, 0), Wc);
    int wlo_al = wlo & ~3;
    int wwid = min(whi - wlo_al, WST);

    int t      = threadIdx.x;
    int lane_w = t & 31;
    int cslot  = t >> 5;               // 0..1
    int wp4    = lane_w * 4;           // this lane's 4-column slot

    const int plane_stride = Hc * Wc;  // 32768

    // ---- Phase 1: rowmax -> LDS (exact-nh unroll, wave-uniform branch) ----
    if (nh > 0 && wp4 < wwid) {
        const float* plane =
            feats + ((size_t)(rb * Cc + c0 + cslot) * Hc) * Wc;
        int goff = wlo_al + wp4;
        switch (nh) {
        case 1:  stage_rows<1>(plane, plane_stride, Wc, hs, goff, wp4, smax, cslot); break;
        case 2:  stage_rows<2>(plane, plane_stride, Wc, hs, goff, wp4, smax, cslot); break;
        case 3:  stage_rows<3>(plane, plane_stride, Wc, hs, goff, wp4, smax, cslot); break;
        case 4:  stage_rows<4>(plane, plane_stride, Wc, hs, goff, wp4, smax, cslot); break;
        default: stage_rows<5>(plane, plane_stride, Wc, hs, goff, wp4, smax, cslot); break;
        }
    }
    __syncthreads();

    // ---- Phase 2: colmax from LDS (fixed 5-wide masked unroll), store ----
    int pw = lane_w;
    int ws = (int)floorf((float)pw * bsw) + rsw;
    int we = (int)ceilf((float)(pw + 1) * bsw) + rsw;
    ws = min(max(ws, 0), Wc);
    we = min(max(we, 0), Wc);

    bool pad   = (ws >= rew);
    bool empty = (he <= hs) || (we <= ws);

    size_t obase = (((size_t)n * Cc + c0 + cslot) * PHB + ph) * PWB + pw;
    if (pad || empty) {
#pragma unroll
        for (int j = 0; j < 4; ++j)
            out[obase + (size_t)(2 * j) * (PHB * PWB)] = 0.0f;
    } else {
        int base = ws - wlo_al;        // >= 0
        int nw   = we - ws;            // 1..5 (bsw <= 3.375)
#pragma unroll
        for (int j = 0; j < 4; ++j) {
            const float* row = &smax[(cslot + 2 * j) * WST + base];
            float m = -1e37f;
#pragma unroll
            for (int i = 0; i < 5; ++i) {        // 5 independent ds_reads,
                float v = row[i];                // masked beyond nw
                m = (i < nw) ? fmaxf(m, v) : m;
            }
            out[obase + (size_t)(2 * j) * (PHB * PWB)] = m;
        }
    }
}

extern "C" void kernel_launch(void* const* d_in, const int* in_sizes, int n_in,
                              void* d_out, int out_size, void* d_ws, size_t ws_size,
                              hipStream_t stream) {
    const float* feats = (const float*)d_in[0];
    const float* rois  = (const float*)d_in[1];
    float* out = (float*)d_out;

    const int Cc = 128, Hc = 64, Wc = 512;
    int nroi = in_sizes[1] / 5;
    int blocks = nroi * PHB * (Cc / CHB);   // 32768

    ocr_roi_pool_kernel<<<blocks, BLK, 0, stream>>>(feats, rois, out, Cc, Hc, Wc);
}